// Round 13
// baseline (1714.108 us; speedup 1.0000x reference)
//
#include <hip/hip_runtime.h>

#define BATCH   16384
#define IN_DIM  1024
#define OUT_DIM 4096
#define K_TOP   409

#define BM 128
#define BN 128
#define BK 16

// ---------------------------------------------------------------- kernel A
__global__ __launch_bounds__(256)
void k_hasneg(const float* __restrict__ x, int n, int* __restrict__ flag) {
    const int stride = gridDim.x * blockDim.x;
    bool neg = false;
    for (int i = blockIdx.x * blockDim.x + threadIdx.x; i < n; i += stride)
        neg |= (x[i] < 0.0f);
    unsigned long long b = __ballot(neg);
    if (b != 0ULL && (threadIdx.x & 63) == 0)
        atomicOr(flag, 1);
}

// ---------------------------------------------------------------- kernel B
// projected[b,o] = sum_i xb[b,i] * W[o,i]   (both K-contiguous, row-major)
//
// CORRECTNESS INVARIANT (do not break in future optimization):
// each output element must be ONE sequential fused-FMA chain over k
// ascending (single accumulator). This matches the reference GEMM
// (XLA->hipBLASLt/Tensile f32 on gfx950: single v_fmac_f32 chain per
// element, ascending k, no split-K) BITWISE, which makes the top-K
// boundary selection exact. Tiling/LDS/vectorization may change freely;
// k-splitting / multi-accumulator / reordering may NOT.
__global__ __launch_bounds__(256)
void k_gemm(const float* __restrict__ x, const float* __restrict__ w,
            float* __restrict__ out, const int* __restrict__ flag) {
    __shared__ float As[BK][BM + 4];
    __shared__ float Bs[BK][BN + 4];
    const int bm = blockIdx.x, bn = blockIdx.y;
    const int tid = threadIdx.x;
    const int tx = tid & 15, ty = tid >> 4;
    const bool bipolar = (*flag == 0);
    float acc[8][8] = {};
    const int lr = tid >> 2;          // 0..63 row for staging
    const int lc = (tid & 3) << 2;    // 0,4,8,12 col group
    const float* xp = x + (size_t)bm * BM * IN_DIM;
    const float* wp = w + (size_t)bn * BN * IN_DIM;

    for (int kt = 0; kt < IN_DIM; kt += BK) {
        #pragma unroll
        for (int rr = 0; rr < BM; rr += 64) {
            float4 v = *(const float4*)&xp[(size_t)(lr + rr) * IN_DIM + kt + lc];
            if (bipolar) {
                v.x = (v.x - 0.5f) * 2.0f; v.y = (v.y - 0.5f) * 2.0f;
                v.z = (v.z - 0.5f) * 2.0f; v.w = (v.w - 0.5f) * 2.0f;
            }
            As[lc + 0][lr + rr] = v.x; As[lc + 1][lr + rr] = v.y;
            As[lc + 2][lr + rr] = v.z; As[lc + 3][lr + rr] = v.w;
        }
        #pragma unroll
        for (int rr = 0; rr < BN; rr += 64) {
            float4 v = *(const float4*)&wp[(size_t)(lr + rr) * IN_DIM + kt + lc];
            Bs[lc + 0][lr + rr] = v.x; Bs[lc + 1][lr + rr] = v.y;
            Bs[lc + 2][lr + rr] = v.z; Bs[lc + 3][lr + rr] = v.w;
        }
        __syncthreads();
        #pragma unroll
        for (int kk = 0; kk < BK; ++kk) {
            float a[8], b[8];
            *(float4*)&a[0] = *(const float4*)&As[kk][ty * 8];
            *(float4*)&a[4] = *(const float4*)&As[kk][ty * 8 + 4];
            *(float4*)&b[0] = *(const float4*)&Bs[kk][tx * 8];
            *(float4*)&b[4] = *(const float4*)&Bs[kk][tx * 8 + 4];
            #pragma unroll
            for (int i = 0; i < 8; ++i)
                #pragma unroll
                for (int j = 0; j < 8; ++j)
                    acc[i][j] = fmaf(a[i], b[j], acc[i][j]);
        }
        __syncthreads();
    }
    #pragma unroll
    for (int i = 0; i < 8; ++i) {
        size_t ro = (size_t)(bm * BM + ty * 8 + i) * OUT_DIM + bn * BN + tx * 8;
        *(float4*)&out[ro]     = make_float4(acc[i][0], acc[i][1], acc[i][2], acc[i][3]);
        *(float4*)&out[ro + 4] = make_float4(acc[i][4], acc[i][5], acc[i][6], acc[i][7]);
    }
}

// ---------------------------------------------------------------- kernel C
// one block per row. NAIVE selector on MY OWN f32 GEMM values (which are
// bitwise the reference's values if the ref is any single-ascending-FMA-
// chain f32 GEMM): radix-select the K-th largest value tf, then
// mask = (v >= tf)  -- tie-INCLUSIVE, exactly the reference's
// `projected >= threshold` (selects K+1 elements on f32-tie rows, the
// ~1-row case that every previous borderline-reranking round dropped).
// encoded = relu(v)*mask; L2 normalize; write in place.
// NO borderline recompute, NO f64, NO CPU replicas.
__global__ __launch_bounds__(256)
void k_select(float* __restrict__ po) {
    __shared__ float sv[OUT_DIM];           // 16 KB: the row
    __shared__ unsigned int bins[256];
    __shared__ unsigned int wsum[4];
    __shared__ int s_selb, s_knew;
    __shared__ float fred[4];

    const int row = blockIdx.x;
    const int tid = threadIdx.x;
    float* prow = po + (size_t)row * OUT_DIM;

    for (int j = tid; j < OUT_DIM; j += 256) sv[j] = prow[j];
    __syncthreads();

    // ---- 4-pass MSB radix select of the K-th largest monotone key
    unsigned int prefix = 0;
    int k = K_TOP;
    #pragma unroll 1
    for (int pass = 0; pass < 4; ++pass) {
        const int s = 24 - pass * 8;
        bins[tid] = 0;
        __syncthreads();
        const unsigned int pmask = (pass == 0) ? 0u : (0xFFFFFFFFu << (s + 8));
        for (int j = tid; j < OUT_DIM; j += 256) {
            unsigned int u = __float_as_uint(sv[j]);
            unsigned int key = (u & 0x80000000u) ? ~u : (u | 0x80000000u);
            if ((key & pmask) == (prefix & pmask))
                atomicAdd(&bins[(key >> s) & 255u], 1u);
        }
        __syncthreads();
        const int b = 255 - tid;               // descending byte order
        const unsigned int c = bins[b];
        unsigned int sc = c;                   // inclusive scan over tid
        #pragma unroll
        for (int off = 1; off < 64; off <<= 1) {
            unsigned int t2 = __shfl_up(sc, off);
            if ((tid & 63) >= off) sc += t2;
        }
        if ((tid & 63) == 63) wsum[tid >> 6] = sc;
        __syncthreads();
        for (int wv = 0; wv < (tid >> 6); ++wv) sc += wsum[wv];
        // sc = count of keys with byte >= b (within prefix)
        if ((int)sc >= k && (int)(sc - c) < k) {
            s_selb = b;
            s_knew = k - (int)(sc - c);
        }
        __syncthreads();
        prefix |= ((unsigned int)s_selb) << s;
        k = s_knew;
        __syncthreads();
    }
    const unsigned int tu = (prefix & 0x80000000u) ? (prefix ^ 0x80000000u) : ~prefix;
    const float tf = __uint_as_float(tu);      // K-th largest value (exact)

    // ---- encode = relu(v) * (v >= tf), norm, write normalized in place
    float nrm2 = 0.0f;
    for (int j = tid; j < OUT_DIM; j += 256) {
        float v = sv[j];
        float e = (v >= tf && v > 0.0f) ? v : 0.0f;
        sv[j] = e;
        nrm2 += e * e;
    }
    #pragma unroll
    for (int off = 32; off > 0; off >>= 1)
        nrm2 += __shfl_down(nrm2, off);
    if ((tid & 63) == 0) fred[tid >> 6] = nrm2;
    __syncthreads();
    const float total = fred[0] + fred[1] + fred[2] + fred[3];
    const float inv = 1.0f / fmaxf(sqrtf(total), 1e-12f);
    for (int j = tid; j < OUT_DIM; j += 256) prow[j] = sv[j] * inv;
}

// ---------------------------------------------------------------- launch
extern "C" void kernel_launch(void* const* d_in, const int* in_sizes, int n_in,
                              void* d_out, int out_size, void* d_ws, size_t ws_size,
                              hipStream_t stream) {
    const float* x = (const float*)d_in[0];
    const float* w = (const float*)d_in[1];
    float* out = (float*)d_out;
    int* flag = (int*)d_ws;

    hipMemsetAsync(flag, 0, sizeof(int), stream);
    k_hasneg<<<2048, 256, 0, stream>>>(x, BATCH * IN_DIM, flag);

    dim3 g(BATCH / BM, OUT_DIM / BN);
    k_gemm<<<g, 256, 0, stream>>>(x, w, out, flag);

    k_select<<<BATCH, 256, 0, stream>>>(out);
}

// Round 14
// 1207.305 us; speedup vs baseline: 1.4198x; 1.4198x over previous
//
#include <hip/hip_runtime.h>

#define BATCH   16384
#define IN_DIM  1024
#define OUT_DIM 4096
#define K_TOP   409
#define NB_CAP  128

typedef _Float16 half8  __attribute__((ext_vector_type(8)));
typedef _Float16 half4v __attribute__((ext_vector_type(4)));
typedef float    f32x4  __attribute__((ext_vector_type(4)));

// ---------------------------------------------------------------- kernel A
__global__ __launch_bounds__(256)
void k_hasneg(const float* __restrict__ x, int n, int* __restrict__ flag) {
    const int stride = gridDim.x * blockDim.x;
    bool neg = false;
    for (int i = blockIdx.x * blockDim.x + threadIdx.x; i < n; i += stride)
        neg |= (x[i] < 0.0f);
    unsigned long long b = __ballot(neg);
    if (b != 0ULL && (threadIdx.x & 63) == 0)
        atomicOr(flag, 1);
}

// ---------------------------------------------------------------- kernel B
// FAST approximate projected[b,o] = sum_k f16(xb[b,k]) * f16(W[o,k]),
// f32 MFMA accumulate. |fast - exact| <~ 2e-3 absolute worst-case;
// k_select's borderline replica (the r13-proven exact chain) recovers
// bit-exact selection. Tile 128x128, BK=64, 4 waves (2x2), each wave
// 64x64 via 4x4 mfma_f32_16x16x32_f16 fragments.
// LDS tiles [128 rows][64 k] f16, XOR-swizzled at 16B-slot granularity
// (slot ^= row&7) so fragment ds_read_b128 is ~2 lanes/bank (free).
__global__ __launch_bounds__(256)
void k_gemm(const float* __restrict__ x, const float* __restrict__ w,
            float* __restrict__ out, const int* __restrict__ flag) {
    __shared__ _Float16 Ah[128 * 64];
    __shared__ _Float16 Bh[128 * 64];
    const int tid = threadIdx.x;
    const int bm = blockIdx.x, bn = blockIdx.y;
    const bool bipolar = (*flag == 0);
    const int lane = tid & 63;
    const int wv = tid >> 6;
    const int wm = wv >> 1, wn = wv & 1;     // wave -> 64x64 quadrant
    const int lr = lane & 15, lk = lane >> 4;

    const int sr = tid >> 1;                 // staging row 0..127
    const int sc = (tid & 1) * 32;           // staging col half
    const float* xr = x + (size_t)(bm * 128 + sr) * IN_DIM;
    const float* wrow = w + (size_t)(bn * 128 + sr) * IN_DIM;

    f32x4 acc[4][4] = {};

    for (int kt = 0; kt < IN_DIM; kt += 64) {
        __syncthreads();                     // protect LDS reuse
        #pragma unroll
        for (int i = 0; i < 8; ++i) {
            const int c = sc + i * 4;
            const int off = sr * 64 + ((((c >> 3) ^ (sr & 7))) << 3) + (c & 7);
            float4 v = *(const float4*)&xr[kt + c];
            if (bipolar) {
                v.x = (v.x - 0.5f) * 2.0f; v.y = (v.y - 0.5f) * 2.0f;
                v.z = (v.z - 0.5f) * 2.0f; v.w = (v.w - 0.5f) * 2.0f;
            }
            half4v hv = { (_Float16)v.x, (_Float16)v.y,
                          (_Float16)v.z, (_Float16)v.w };
            *(half4v*)&Ah[off] = hv;
            float4 u = *(const float4*)&wrow[kt + c];
            half4v hu = { (_Float16)u.x, (_Float16)u.y,
                          (_Float16)u.z, (_Float16)u.w };
            *(half4v*)&Bh[off] = hu;
        }
        __syncthreads();
        #pragma unroll
        for (int h = 0; h < 2; ++h) {        // two K=32 steps per tile
            half8 af[4], bf[4];
            #pragma unroll
            for (int i = 0; i < 4; ++i) {
                const int ra = wm * 64 + i * 16 + lr;
                const int sa = (h * 4 + lk) ^ (ra & 7);
                af[i] = *(const half8*)&Ah[ra * 64 + (sa << 3)];
                const int rb = wn * 64 + i * 16 + lr;
                const int sb = (h * 4 + lk) ^ (rb & 7);
                bf[i] = *(const half8*)&Bh[rb * 64 + (sb << 3)];
            }
            #pragma unroll
            for (int i = 0; i < 4; ++i)
                #pragma unroll
                for (int j = 0; j < 4; ++j)
                    acc[i][j] = __builtin_amdgcn_mfma_f32_16x16x32_f16(
                        af[i], bf[j], acc[i][j], 0, 0, 0);
        }
    }
    // epilogue: C/D layout col=lane&15, row=(lane>>4)*4+q  [guide m89/m91]
    #pragma unroll
    for (int i = 0; i < 4; ++i)
        #pragma unroll
        for (int j = 0; j < 4; ++j)
            #pragma unroll
            for (int q = 0; q < 4; ++q) {
                const int row = bm * 128 + wm * 64 + i * 16 + lk * 4 + q;
                const int col = bn * 128 + wn * 64 + j * 16 + lr;
                out[(size_t)row * OUT_DIM + col] = acc[i][j][q];
            }
}

// ---------------------------------------------------------------- kernel C
// one block per row: radix-select K-th largest of the FAST values, then
// recompute the +-8e-3 borderline window with the EXACT reference chain
// (r13-proven: single accumulator, ascending-k __fmaf_rn), select window
// members by replica value with >=-tie semantics, output replica values
// for selected window elems. relu, L2 normalize, in place.
__global__ __launch_bounds__(256)
void k_select(float* __restrict__ po, const float* __restrict__ x,
              const float* __restrict__ w, const int* __restrict__ flag) {
    __shared__ float sv[OUT_DIM];           // 16 KB: the row (fast values)
    __shared__ unsigned int bins[256];
    __shared__ unsigned int wsum[4];
    __shared__ int s_selb, s_knew;
    __shared__ unsigned int s_hi, s_nb;
    __shared__ int bl_idx[NB_CAP];
    __shared__ float bl_np[NB_CAP];
    __shared__ unsigned char bl_in[NB_CAP];
    __shared__ float fred[4];
    __shared__ float xs[IN_DIM];            // 4 KB: x_bipolar row (exact)

    const int row = blockIdx.x;
    const int tid = threadIdx.x;
    float* prow = po + (size_t)row * OUT_DIM;

    for (int j = tid; j < OUT_DIM; j += 256) sv[j] = prow[j];
    __syncthreads();

    // ---- 4-pass MSB radix select of the K-th largest monotone key
    unsigned int prefix = 0;
    int k = K_TOP;
    #pragma unroll 1
    for (int pass = 0; pass < 4; ++pass) {
        const int s = 24 - pass * 8;
        bins[tid] = 0;
        __syncthreads();
        const unsigned int pmask = (pass == 0) ? 0u : (0xFFFFFFFFu << (s + 8));
        for (int j = tid; j < OUT_DIM; j += 256) {
            unsigned int u = __float_as_uint(sv[j]);
            unsigned int key = (u & 0x80000000u) ? ~u : (u | 0x80000000u);
            if ((key & pmask) == (prefix & pmask))
                atomicAdd(&bins[(key >> s) & 255u], 1u);
        }
        __syncthreads();
        const int b = 255 - tid;               // descending byte order
        const unsigned int c = bins[b];
        unsigned int sc = c;                   // inclusive scan over tid
        #pragma unroll
        for (int off = 1; off < 64; off <<= 1) {
            unsigned int t2 = __shfl_up(sc, off);
            if ((tid & 63) >= off) sc += t2;
        }
        if ((tid & 63) == 63) wsum[tid >> 6] = sc;
        __syncthreads();
        for (int wq = 0; wq < (tid >> 6); ++wq) sc += wsum[wq];
        if ((int)sc >= k && (int)(sc - c) < k) {
            s_selb = b;
            s_knew = k - (int)(sc - c);
        }
        __syncthreads();
        prefix |= ((unsigned int)s_selb) << s;
        k = s_knew;
        __syncthreads();
    }
    const unsigned int tu = (prefix & 0x80000000u) ? (prefix ^ 0x80000000u) : ~prefix;
    const float tf = __uint_as_float(tu);      // K-th largest FAST value
    const float delta = 8e-3f;                 // >> fp16-GEMM max error ~2e-3
    const float thi = tf + delta, tlo = tf - delta;

    // ---- classify: certainly-in vs borderline
    if (tid == 0) { s_hi = 0; s_nb = 0; }
    __syncthreads();
    for (int j = tid; j < OUT_DIM; j += 256) {
        float v = sv[j];
        if (v > thi) atomicAdd(&s_hi, 1u);
        else if (v >= tlo) {
            unsigned int p = atomicAdd(&s_nb, 1u);
            if (p < NB_CAP) bl_idx[p] = j;
        }
    }
    __syncthreads();
    const int hi = (int)s_hi;
    int nb = (int)s_nb; if (nb > NB_CAP) nb = NB_CAP;
    int krem = K_TOP - hi; if (krem > nb) krem = nb; if (krem < 0) krem = 0;
    const bool need = (nb != krem);

    if (need) {
        const bool bipolar = (*flag == 0);
        for (int i = tid; i < IN_DIM; i += 256) {
            float xv = x[(size_t)row * IN_DIM + i];
            xs[i] = bipolar ? __fmul_rn(__fadd_rn(xv, -0.5f), 2.0f) : xv;
        }
        __syncthreads();
        // EXACT reference chain (bitwise r13): single acc, ascending k, FMA.
        for (int m = tid; m < nb; m += 256) {
            const float* wr = w + (size_t)bl_idx[m] * IN_DIM;
            float p = 0.0f;
            for (int i = 0; i < IN_DIM; ++i)
                p = __fmaf_rn(xs[i], wr[i], p);
            bl_np[m] = p;
        }
        __syncthreads();
        if (tid == 0) {
            for (int m = 0; m < nb; ++m) bl_in[m] = 0;
            if (krem > 0) {
                float thr_b = 1e30f;
                for (int it = 0; it < krem; ++it) {
                    int best = -1; float bv = -1e30f;
                    for (int m = 0; m < nb; ++m)
                        if (!bl_in[m] && bl_np[m] > bv) { bv = bl_np[m]; best = m; }
                    if (best >= 0) { bl_in[best] = 1; thr_b = bv; }
                }
                // >=-tie semantics (reference keeps K+1 on exact ties)
                for (int m = 0; m < nb; ++m)
                    bl_in[m] = (bl_np[m] >= thr_b) ? 1 : 0;
            }
        }
        __syncthreads();
    }

    // ---- encode = relu * mask, norm, write normalized in place
    float nrm2 = 0.0f;
    for (int j = tid; j < OUT_DIM; j += 256) {
        float v = sv[j];
        bool sel = false;
        float val = v;
        if (v > thi) sel = true;
        else if (v >= tlo) {
            if (!need) sel = true;
            else {
                for (int m = 0; m < nb; ++m)
                    if (bl_idx[m] == j) {
                        sel = (bl_in[m] != 0);
                        val = bl_np[m];       // exact reference value
                        break;
                    }
            }
        }
        float e = (sel && val > 0.0f) ? val : 0.0f;
        sv[j] = e;
        nrm2 += e * e;
    }
    #pragma unroll
    for (int off = 32; off > 0; off >>= 1)
        nrm2 += __shfl_down(nrm2, off);
    if ((tid & 63) == 0) fred[tid >> 6] = nrm2;
    __syncthreads();
    const float total = fred[0] + fred[1] + fred[2] + fred[3];
    const float inv = 1.0f / fmaxf(sqrtf(total), 1e-12f);
    for (int j = tid; j < OUT_DIM; j += 256) prow[j] = sv[j] * inv;
}

// ---------------------------------------------------------------- launch
extern "C" void kernel_launch(void* const* d_in, const int* in_sizes, int n_in,
                              void* d_out, int out_size, void* d_ws, size_t ws_size,
                              hipStream_t stream) {
    const float* x = (const float*)d_in[0];
    const float* w = (const float*)d_in[1];
    float* out = (float*)d_out;
    int* flag = (int*)d_ws;

    hipMemsetAsync(flag, 0, sizeof(int), stream);
    k_hasneg<<<2048, 256, 0, stream>>>(x, BATCH * IN_DIM, flag);

    dim3 g(BATCH / 128, OUT_DIM / 128);
    k_gemm<<<g, 256, 0, stream>>>(x, w, out, flag);

    k_select<<<BATCH, 256, 0, stream>>>(out, x, w, flag);
}